// Round 2
// baseline (140.990 us; speedup 1.0000x reference)
//
#include <hip/hip_runtime.h>

// Problem constants: nframes=8, nloc=8192, nnei=128, nall=16384, ntypes=4,
// nspline=2000. rmin=0, hh=f32(0.005), rcut=6.0.
constexpr int NFRAMES = 8;
constexpr int NLOC    = 8192;
constexpr int NNEI    = 128;
constexpr int NALL    = 16384;
constexpr int NTYPES  = 4;
constexpr int NSPLINE = 2000;
constexpr int KLIVE   = 1200;   // rr<6 => uu=rr*200<1200 => live bins [0,1200)
constexpr int KBLK    = 8;      // old lds kernel: chunks per bucket

// r18 chunked-LDS-gather parameters
constexpr int CHUNK   = 4096;         // atoms per staged pack chunk (64 KiB)
constexpr int NCHUNK  = NALL / CHUNK; // 4
constexpr int SLICES2 = 8;            // blocks per bucket (256 blocks = 1/CU)
constexpr int ITN     = 16;           // register accumulators: covers cnt<=4096
constexpr int OVN     = 16;           // overflow its: ITN+OVN covers cnt<=8192

// Opaque dataflow barrier: keeps the verified f32 rounding chain intact.
#define FP_BAR(x) asm volatile("" : "+v"(x))

__global__ __launch_bounds__(256) void pack_kernel(
    const float* __restrict__ coord, const int* __restrict__ atype,
    float4* __restrict__ pack, int* __restrict__ cnts)
{
    int t = blockIdx.x * 256 + threadIdx.x;   // grid sized exactly
    if (blockIdx.x == 0 && threadIdx.x < NFRAMES * NTYPES) cnts[threadIdx.x] = 0;
    float4 v;
    v.x = coord[3 * (size_t)t + 0];
    v.y = coord[3 * (size_t)t + 1];
    v.z = coord[3 * (size_t)t + 2];
    v.w = __int_as_float(atype[t]);
    pack[t] = v;
}

// Two-level aggregation (r14, ~3us): LDS histogram, 1 global atomic per
// (block,type), then scatter.
__global__ __launch_bounds__(256) void bucket_kernel(
    const int* __restrict__ atype, int* __restrict__ perm,
    int* __restrict__ cnts)
{
    __shared__ int hist[NTYPES];
    __shared__ int base[NTYPES];
    const int t = blockIdx.x * 256 + threadIdx.x;   // 0..65535
    const int f = t >> 13;                          // block-uniform (256|8192)
    const int i = t & (NLOC - 1);
    const int ty = atype[(size_t)f * NALL + i];

    if (threadIdx.x < NTYPES) hist[threadIdx.x] = 0;
    __syncthreads();
    const int my_off = atomicAdd(&hist[ty], 1);     // LDS atomic (fast)
    __syncthreads();
    if (threadIdx.x < NTYPES)
        base[threadIdx.x] = atomicAdd(&cnts[f * NTYPES + threadIdx.x],
                                      hist[threadIdx.x]);
    __syncthreads();
    perm[(size_t)(f * NTYPES + ty) * NLOC + base[ty] + my_off] = i;
}

// r18: chunk-compact each neighbor row. Output row = valid neighbors grouped
// by chunk (j>>12), invalid (j<0) dropped, stored as ushort WITHIN-CHUNK
// index (j&4095; chunk implied by position). Order within a sublist does not
// matter (f64 accumulation). offs[row] = int4 prefix ends (e0,e1,e2,e3).
__global__ __launch_bounds__(256) void compact_kernel(
    const int* __restrict__ nlist, ushort* __restrict__ cl,
    int4* __restrict__ offs)
{
    const int w    = (blockIdx.x * 256 + threadIdx.x) >> 6;  // row 0..65535
    const int lane = threadIdx.x & 63;
    const int* __restrict__ row = nlist + (size_t)w * NNEI;
    ushort* __restrict__ crow = cl + (size_t)w * NNEI;
    const int j0 = row[lane];
    const int j1 = row[64 + lane];
    const unsigned long long lt = (1ull << lane) - 1ull;
    int base = 0;
    int e[NCHUNK];
#pragma unroll
    for (int c = 0; c < NCHUNK; ++c) {
        const bool m0 = (j0 >= 0) && ((j0 >> 12) == c);
        const bool m1 = (j1 >= 0) && ((j1 >> 12) == c);
        const unsigned long long b0 = __ballot(m0);
        const unsigned long long b1 = __ballot(m1);
        const int n0 = __popcll(b0);
        if (m0) crow[base + __popcll(b0 & lt)] = (ushort)(j0 & (CHUNK - 1));
        if (m1) crow[base + n0 + __popcll(b1 & lt)] =
            (ushort)(j1 & (CHUNK - 1));
        base += n0 + __popcll(b1);
        e[c] = base;
    }
    if (lane == 0) offs[w] = make_int4(e[0], e[1], e[2], e[3]);
}

// VERIFIED ref chain (r11, absmax 3.8e-6 — DO NOT TOUCH):
//   ss = fma(dz,dz, fma(dx,dx, dy*dy)); rr = CR sqrtf; uu = rr * f32(1/hh);
//   idx = trunc(uu); poly/sum in f64 (post-bin). Energy zero iff
//   !valid | rr>=6; live => idx in [0,1199].
// Invalid lanes pass c={0,0,0,0}: dx..ss are finite, valid=false skips ltab.
__device__ __forceinline__ double nb_energy_lds(
    float4 c, bool valid, float xl, float yl, float zl,
    float rmin, float recip, const float4* __restrict__ ltab)
{
    float dx = c.x - xl;  FP_BAR(dx);
    float dy = c.y - yl;  FP_BAR(dy);
    float dz = c.z - zl;  FP_BAR(dz);
    float my = dy * dy;                    FP_BAR(my);
    float t1 = __builtin_fmaf(dx, dx, my); FP_BAR(t1);   // canonical inner
    float ss = __builtin_fmaf(dz, dz, t1); FP_BAR(ss);
    float rr = sqrtf(ss);                  FP_BAR(rr);   // CR
    float num = rr - rmin;               FP_BAR(num);    // rmin=0: num==rr
    float uu  = num * recip;             FP_BAR(uu);     // recip-mul form
    double e = 0.0;
    if (valid && rr < 6.0f) {
        int    idx = (int)uu;                // in [0,1199] here
        double t   = (double)uu - (double)idx;           // exact (Sterbenz)
        int    tj  = __float_as_int(c.w);
        float4 cf  = ltab[tj * KLIVE + idx];             // ds_read_b128
        e = (((double)cf.x * t + (double)cf.y) * t + (double)cf.z) * t
            + (double)cf.w;
    }
    return e;
}

// r18 helper: energy of one loc's chunk-c sublist (neighbors staged in cpack,
// compacted row entries are within-chunk indices).
__device__ __forceinline__ double row_chunk_energy(
    int c, const int4 pe, const ushort* __restrict__ crow,
    const float4 pl, int lih, float rmin, float recip,
    const float4* __restrict__ cpack, const float4* __restrict__ ltab)
{
    const int beg = (c == 0) ? 0 : ((c == 1) ? pe.x : ((c == 2) ? pe.y : pe.z));
    const int end = (c == 0) ? pe.x
                             : ((c == 1) ? pe.y : ((c == 2) ? pe.z : pe.w));
    double es = 0.0;
    for (int b = beg; b < end; b += 32) {
        const bool lv = (b + lih) < end;
        float4 cc = make_float4(0.f, 0.f, 0.f, 0.f);
        if (lv) cc = cpack[crow[b + lih]];                // LDS gather
        es += nb_energy_lds(cc, lv, pl.x, pl.y, pl.z, rmin, recip, ltab);
    }
    return es;
}

// r18 main kernel: pack gathers moved from global (TA ~2.2cyc/lane-req, the
// r16 bottleneck) into LDS (~0.5cyc/lane-req bank cost). pack staged in 4
// chunks of 4096 atoms; per-loc partials held in registers across chunk
// swaps (eacc[ITN], compile-time indexed under full unroll); one f64
// shuffle-butterfly per loc at write-out. 256 blocks = 1/CU (146KB LDS).
// Overflow path (cnt>4096) keeps correctness for skewed type distributions
// (never hot for this input: cnt ~ 2048).
__global__ __launch_bounds__(1024) void pairtab_chunk_kernel(
    const float4* __restrict__ pack,
    const float*  __restrict__ tab,       // [NTYPES][NTYPES][NSPLINE][4]
    const float*  __restrict__ tab_info,  // [rmin, hh, nspline, ntypes]
    const ushort* __restrict__ cl,        // chunk-compacted neighbor rows
    const int4*   __restrict__ offs,      // per-row prefix ends
    const int*    __restrict__ perm,      // [32][NLOC] bucketed loc ids
    const int*    __restrict__ cnts,      // [32]
    float*        __restrict__ out)       // [NFRAMES][NLOC]
{
    __shared__ float4 ltab[NTYPES * KLIVE];   // 76800 B
    __shared__ float4 cpack[CHUNK];           // 65536 B
    __shared__ double accov[OVN * 32];        //  4096 B  (146432 total)

    const int bucket = blockIdx.x >> 3;        // / SLICES2
    const int slice  = blockIdx.x & (SLICES2 - 1);
    const int f  = bucket >> 2;
    const int ti = bucket & 3;

    // stage tab[ti][tj][0..1199][:] -> ltab[tj*1200+k] (coalesced float4)
    const float4* tsrc = (const float4*)tab + (size_t)ti * (NTYPES * NSPLINE);
    for (int idx = threadIdx.x; idx < NTYPES * KLIVE; idx += 1024) {
        int tj = idx / KLIVE;
        int k  = idx - tj * KLIVE;
        ltab[idx] = tsrc[tj * NSPLINE + k];
    }
    if (threadIdx.x < OVN * 32) accov[threadIdx.x] = 0.0;

    const float rmin = tab_info[0];
    const float hh   = tab_info[1];
    // CR f32 reciprocal via f64 + single rounding == f32 divide(1,hh) == 200.0f
    float recip = (float)(1.0 / (double)hh);  FP_BAR(recip);

    const int cnt  = cnts[bucket];
    const int lane = threadIdx.x & 63;
    const int wave = (int)(threadIdx.x >> 6); // 0..15
    const int half = lane >> 5;
    const int lih  = lane & 31;
    const int slot = (wave << 1) | half;      // 0..31
    const size_t fb = (size_t)f * NALL;
    const int*    __restrict__ permb = perm + (size_t)bucket * NLOC;
    const int4*   __restrict__ offf  = offs + (size_t)f * NLOC;
    const ushort* __restrict__ clf   = cl   + (size_t)f * NLOC * NNEI;

    double eacc[ITN];
#pragma unroll
    for (int i = 0; i < ITN; ++i) eacc[i] = 0.0;

#pragma unroll 1
    for (int c = 0; c < NCHUNK; ++c) {
        __syncthreads();                       // prev-chunk readers done
        {
            const float4* psrc = pack + fb + c * CHUNK;
            for (int k = threadIdx.x; k < CHUNK; k += 1024) cpack[k] = psrc[k];
        }
        __syncthreads();

        // hot path: register accumulation, compile-time it indices
#pragma unroll
        for (int it = 0; it < ITN; ++it) {
            const int s = slice * 32 + it * (SLICES2 * 32) + slot;
            if (s < cnt) {
                const int loc = permb[s];
                eacc[it] += row_chunk_energy(c, offf[loc],
                                             clf + (size_t)loc * NNEI,
                                             pack[fb + loc], lih, rmin, recip,
                                             cpack, ltab);
            }
        }

        // cold overflow path (cnt > 4096): butterfly per (loc,chunk) + LDS acc
        int ov = 0;
        for (int s0 = slice * 32 + ITN * (SLICES2 * 32); s0 < cnt;
             s0 += SLICES2 * 32, ++ov) {
            const int s = s0 + slot;
            double es = 0.0;
            if (s < cnt) {
                const int loc = permb[s];
                es = row_chunk_energy(c, offf[loc], clf + (size_t)loc * NNEI,
                                      pack[fb + loc], lih, rmin, recip,
                                      cpack, ltab);
            }
#pragma unroll
            for (int off = 16; off >= 1; off >>= 1)
                es += __shfl_xor(es, off, 64);
            if (s < cnt && lih == 0) accov[ov * 32 + slot] += es;
        }
    }
    __syncthreads();

    // write-out: one 32-lane butterfly per loc
#pragma unroll
    for (int it = 0; it < ITN; ++it) {
        const int s = slice * 32 + it * (SLICES2 * 32) + slot;
        if (s < cnt) {
            double es = eacc[it];
#pragma unroll
            for (int off = 16; off >= 1; off >>= 1)
                es += __shfl_xor(es, off, 64);
            if (lih == 0)
                out[(size_t)f * NLOC + permb[s]] = (float)(0.5 * es);
        }
    }
    {
        int ov = 0;
        for (int s0 = slice * 32 + ITN * (SLICES2 * 32); s0 < cnt;
             s0 += SLICES2 * 32, ++ov) {
            const int s = s0 + slot;
            if (s < cnt && lih == 0)
                out[(size_t)f * NLOC + permb[s]] =
                    (float)(0.5 * accov[ov * 32 + slot]);
        }
    }
}

// -------- r16 kernel (kept as mid-ws fallback) --------
__global__ __launch_bounds__(1024, 8) void pairtab_lds_kernel(
    const float4* __restrict__ pack,
    const float*  __restrict__ tab,
    const float*  __restrict__ tab_info,
    const int*    __restrict__ nlist,
    const int*    __restrict__ perm,
    const int*    __restrict__ cnts,
    float*        __restrict__ out)
{
    __shared__ float4 ltab[NTYPES * KLIVE];   // 76800 B

    const int bucket = blockIdx.x >> 3;       // / KBLK
    const int chunk  = blockIdx.x & (KBLK - 1);
    const int f  = bucket >> 2;
    const int ti = bucket & 3;

    const float4* tsrc = (const float4*)tab + (size_t)ti * (NTYPES * NSPLINE);
    for (int idx = threadIdx.x; idx < NTYPES * KLIVE; idx += 1024) {
        int tj = idx / KLIVE;
        int k  = idx - tj * KLIVE;
        ltab[idx] = tsrc[tj * NSPLINE + k];
    }
    __syncthreads();

    const float rmin = tab_info[0];
    const float hh   = tab_info[1];
    float recip = (float)(1.0 / (double)hh);  FP_BAR(recip);

    const int cnt  = cnts[bucket];
    const int lane = threadIdx.x & 63;
    const int wave = (int)(threadIdx.x >> 6); // 0..15
    const int half = lane >> 5;
    const int lih  = lane & 31;
    const size_t fb = (size_t)f * NALL;
    const int* __restrict__ permb = perm + (size_t)bucket * NLOC;
    const int* __restrict__ nlf   = nlist + (size_t)f * NLOC * NNEI;
    const float4 zero4 = make_float4(0.f, 0.f, 0.f, 0.f);

    for (int s0 = chunk * 32; s0 < cnt; s0 += KBLK * 32) {
        const int s = s0 + wave * 2 + half;
        const bool active = s < cnt;          // uniform per 32-lane half
        const int loc = active ? permb[s] : 0;

        const float4 pl = pack[fb + loc];     // half-uniform broadcast
        const float xl = pl.x, yl = pl.y, zl = pl.z;

        const int4 jj = ((const int4*)(nlf + (size_t)loc * NNEI))[lih];

        float4 c0 = zero4, c1 = zero4, c2 = zero4, c3 = zero4;
        if (jj.x >= 0) c0 = pack[fb + jj.x];
        if (jj.y >= 0) c1 = pack[fb + jj.y];
        if (jj.z >= 0) c2 = pack[fb + jj.z];
        if (jj.w >= 0) c3 = pack[fb + jj.w];

        double esum = nb_energy_lds(c0, jj.x >= 0, xl, yl, zl, rmin, recip, ltab)
                    + nb_energy_lds(c1, jj.y >= 0, xl, yl, zl, rmin, recip, ltab)
                    + nb_energy_lds(c2, jj.z >= 0, xl, yl, zl, rmin, recip, ltab)
                    + nb_energy_lds(c3, jj.w >= 0, xl, yl, zl, rmin, recip, ltab);

#pragma unroll
        for (int off = 16; off >= 1; off >>= 1)
            esum += __shfl_xor(esum, off, 64);

        if (active && lih == 0) out[(size_t)f * NLOC + loc] = (float)(0.5 * esum);
    }
}

// -------- r12 fallback (used only if ws_size is too small) --------
__device__ __forceinline__ double nb_energy_g(
    float4 c, bool valid, float xl, float yl, float zl,
    float rmin, float recip, const float* __restrict__ tabi)
{
    float dx = c.x - xl;  FP_BAR(dx);
    float dy = c.y - yl;  FP_BAR(dy);
    float dz = c.z - zl;  FP_BAR(dz);
    float my = dy * dy;                    FP_BAR(my);
    float t1 = __builtin_fmaf(dx, dx, my); FP_BAR(t1);
    float ss = __builtin_fmaf(dz, dz, t1); FP_BAR(ss);
    float rr = sqrtf(ss);                  FP_BAR(rr);
    float num = rr - rmin;               FP_BAR(num);
    float uu  = num * recip;             FP_BAR(uu);
    int   idx = (int)uu;
    double t  = (double)uu - (double)idx;
    int clip  = idx < 0 ? 0 : (idx > NSPLINE - 1 ? NSPLINE - 1 : idx);
    int tj    = __float_as_int(c.w);
    const float4 coef =
        *(const float4*)(tabi + (((size_t)tj * NSPLINE + clip) << 2));
    double e = (((double)coef.x * t + (double)coef.y) * t + (double)coef.z) * t
               + (double)coef.w;
    bool zero = (!valid) | (idx > NSPLINE) | (rr >= 6.0f);
    return zero ? 0.0 : e;
}

__global__ __launch_bounds__(256) void pairtab_kernel(
    const float4* __restrict__ pack, const float* __restrict__ tab,
    const float* __restrict__ tab_info, const int* __restrict__ nlist,
    float* __restrict__ out)
{
    const int lane = threadIdx.x & 63;
    const int wid  = (blockIdx.x * 256 + threadIdx.x) >> 6;
    const int half = lane >> 5;
    const int gloc = 2 * wid + half;
    const int f = gloc >> 13;
    const int i = gloc & (NLOC - 1);
    const float rmin = tab_info[0];
    const float hh   = tab_info[1];
    float recip = (float)(1.0 / (double)hh);  FP_BAR(recip);
    const float4 pl = pack[(size_t)f * NALL + i];
    const float xl = pl.x, yl = pl.y, zl = pl.z;
    const int   ti = __float_as_int(pl.w);
    const float* tabi = tab + (size_t)ti * (NTYPES * NSPLINE * 4);
    const int4 jj = ((const int4*)(nlist + (size_t)wid * 256))[lane];
    const int mj0 = jj.x < 0 ? 0 : jj.x, mj1 = jj.y < 0 ? 0 : jj.y;
    const int mj2 = jj.z < 0 ? 0 : jj.z, mj3 = jj.w < 0 ? 0 : jj.w;
    const size_t fb = (size_t)f * NALL;
    const float4 c0 = pack[fb + mj0], c1 = pack[fb + mj1];
    const float4 c2 = pack[fb + mj2], c3 = pack[fb + mj3];
    double esum = nb_energy_g(c0, jj.x >= 0, xl, yl, zl, rmin, recip, tabi)
                + nb_energy_g(c1, jj.y >= 0, xl, yl, zl, rmin, recip, tabi)
                + nb_energy_g(c2, jj.z >= 0, xl, yl, zl, rmin, recip, tabi)
                + nb_energy_g(c3, jj.w >= 0, xl, yl, zl, rmin, recip, tabi);
#pragma unroll
    for (int off = 16; off >= 1; off >>= 1)
        esum += __shfl_xor(esum, off, 64);
    if ((lane & 31) == 0) out[gloc] = (float)(0.5 * esum);
}

extern "C" void kernel_launch(void* const* d_in, const int* in_sizes, int n_in,
                              void* d_out, int out_size, void* d_ws, size_t ws_size,
                              hipStream_t stream)
{
    const float* coord   = (const float*)d_in[0];   // (8,16384,3) f32
    const float* tab     = (const float*)d_in[1];   // (4,4,2000,4) f32
    const float* tabinfo = (const float*)d_in[2];   // (4,) f32
    const int*   atype   = (const int*)d_in[3];     // (8,16384) int32
    const int*   nlist   = (const int*)d_in[4];     // (8,8192,128) int32
    float* out  = (float*)d_out;                    // (8,8192,1) f32

    // ws layout (disjoint, r18 — r17 failed on cl/offs overlap):
    //   pack  @ 0        2 MB   (8*16384*16)
    //   perm  @ 2 MB     1 MB   (32*8192*4)
    //   cnts  @ 3 MB     128 B  (4 KB slot)
    //   offs  @ 3 MB+4K  1 MB   (65536*16)
    //   cl16  @ 4 MB+4K  16 MB  (65536*128*2)
    float4* pack = (float4*)d_ws;
    int*    perm = (int*)((char*)d_ws + 2 * 1024 * 1024);
    int*    cnts = (int*)((char*)d_ws + 3 * 1024 * 1024);
    int4*   offs = (int4*)((char*)d_ws + 3 * 1024 * 1024 + 4096);
    ushort* cl16 = (ushort*)((char*)d_ws + 4 * 1024 * 1024 + 4096);
    const size_t need3 = 20 * 1024 * 1024 + 8192;
    const size_t need1 = 3 * 1024 * 1024 + 128;

    pack_kernel<<<(NFRAMES * NALL) / 256, 256, 0, stream>>>(coord, atype, pack,
                                                            cnts);
    if (ws_size >= need3) {
        bucket_kernel<<<(NFRAMES * NLOC) / 256, 256, 0, stream>>>(atype, perm,
                                                                  cnts);
        compact_kernel<<<(NFRAMES * NLOC) / 4, 256, 0, stream>>>(nlist, cl16,
                                                                 offs);
        pairtab_chunk_kernel<<<NFRAMES * NTYPES * SLICES2, 1024, 0, stream>>>(
            pack, tab, tabinfo, cl16, offs, perm, cnts, out);
    } else if (ws_size >= need1) {
        bucket_kernel<<<(NFRAMES * NLOC) / 256, 256, 0, stream>>>(atype, perm,
                                                                  cnts);
        pairtab_lds_kernel<<<NFRAMES * NTYPES * KBLK, 1024, 0, stream>>>(
            pack, tab, tabinfo, nlist, perm, cnts, out);
    } else {
        pairtab_kernel<<<(NFRAMES * NLOC) / 8, 256, 0, stream>>>(
            pack, tab, tabinfo, nlist, out);
    }
}